// Round 6
// baseline (709.543 us; speedup 1.0000x reference)
//
#include <hip/hip_runtime.h>
#include <hip/hip_bf16.h>
#include <math.h>

#define IN_F    4096
#define OUT_F   4096
#define N_TOK   8192
#define GROUP   128
#define NSTAGE  4
#define NPAIRS  2048   // IN_F/2 pairs per stage
#define QMAXF   15.0
#define ROWS_PW 8      // rows per wave in build_w (amortizes tab/pair loads)

typedef unsigned short u16;
typedef __bf16 bf16x8 __attribute__((ext_vector_type(8)));
typedef float  f32x4  __attribute__((ext_vector_type(4)));

struct alignas(8) U16x4 { u16 x, y, z, w; };

__device__ __forceinline__ u16 f2bf(float f) {
    unsigned u = __float_as_uint(f);
    unsigned r = (u + 0x7fffu + ((u >> 16) & 1u)) >> 16;   // RNE
    return (u16)r;
}

__device__ __forceinline__ void gl_lds16(const void* g, void* l) {
    __builtin_amdgcn_global_load_lds(
        (const __attribute__((address_space(1))) void*)g,
        (__attribute__((address_space(3))) void*)l,
        16, 0, 0);
}

// ---------------------------------------------------------------- tables ----
__global__ void make_tabs(const float* __restrict__ theta,
                          double* __restrict__ ctab, double* __restrict__ stab) {
    int i = blockIdx.x * 256 + threadIdx.x;
    if (i < NSTAGE * NPAIRS) {
        double t = (double)theta[i];
        ctab[i] = cos(t);
        stab[i] = sin(t);
    }
}

// ------------------------------------------------------------- transform ----
// One WAVE per (row-block, group): block-diagonal chain in LDS doubles,
// wave-sync. ROWS_PW rows per wave: pairs/cos/sin/1/cs cached in registers
// (row-invariant), qdq uses one reciprocal per (row,group).
__global__ __launch_bounds__(256) void build_w(
    const float* __restrict__ weight, const float* __restrict__ cs,
    const float* __restrict__ qs, const float* __restrict__ qzp,
    const int* __restrict__ pairs,
    const double* __restrict__ ctab, const double* __restrict__ stab,
    u16* __restrict__ wb) {
    __shared__ double gbuf[4][GROUP];
    const int wave = threadIdx.x >> 6, l = threadIdx.x & 63;
    const int task = blockIdx.x * 4 + wave;    // (4096/ROWS_PW)*32 tasks
    const int ob = task >> 5, g = task & 31;
    const int o0 = ob * ROWS_PW;
    double* gb = gbuf[wave];
    const int e0 = g * GROUP;

    const int2* prs = (const int2*)pairs;      // (i,j) pairs, 8B aligned
    int2   pr_[NSTAGE];
    double c_[NSTAGE], s_[NSTAGE];
#pragma unroll
    for (int r = 0; r < NSTAGE; ++r) {
        pr_[r] = prs[r * (IN_F / 2) + g * 64 + l];
        c_[r]  = ctab[r * NPAIRS + g * 64 + l];
        s_[r]  = stab[r * NPAIRS + g * 64 + l];
    }
    float2 cv = *(const float2*)(cs + e0 + 2 * l);
    const double cvx = (double)cv.x, cvy = (double)cv.y;
    const double rcx = 1.0 / cvx, rcy = 1.0 / cvy;

    for (int o = o0; o < o0 + ROWS_PW; ++o) {
        float2 wv = *(const float2*)(weight + (size_t)o * IN_F + e0 + 2 * l);
        gb[2 * l]     = (double)wv.x * cvx;
        gb[2 * l + 1] = (double)wv.y * cvy;
        __builtin_amdgcn_wave_barrier();

#pragma unroll
        for (int r = 0; r < NSTAGE; ++r) {
            double xi = gb[pr_[r].x], xj = gb[pr_[r].y];
            __builtin_amdgcn_wave_barrier();
            gb[pr_[r].x] =  xi * c_[r] + xj * s_[r];
            gb[pr_[r].y] = -xi * s_[r] + xj * c_[r];
            __builtin_amdgcn_wave_barrier();
        }

        {
            double sc  = fmin(fmax((double)qs[o * 32 + g], 1e-5), 1e5);
            double rzp = fmin(fmax(-rint((double)qzp[o * 32 + g]), 0.0), QMAXF);
            double inv = 1.0 / sc;
#pragma unroll
            for (int e = 2 * l; e <= 2 * l + 1; ++e) {
                double q = rint(gb[e] * inv) + rzp;
                q = fmin(fmax(q, 0.0), QMAXF);
                gb[e] = (q - rzp) * sc;
            }
            __builtin_amdgcn_wave_barrier();
        }

#pragma unroll
        for (int r = NSTAGE - 1; r >= 0; --r) {
            double xi = gb[pr_[r].x], xj = gb[pr_[r].y];
            __builtin_amdgcn_wave_barrier();
            gb[pr_[r].x] = xi * c_[r] - xj * s_[r];
            gb[pr_[r].y] = xi * s_[r] + xj * c_[r];
            __builtin_amdgcn_wave_barrier();
        }

        unsigned lo = f2bf((float)(gb[2 * l]     * rcx));
        unsigned hi = f2bf((float)(gb[2 * l + 1] * rcy));
        *(unsigned*)(wb + (size_t)o * IN_F + e0 + 2 * l) = lo | (hi << 16);
        __builtin_amdgcn_wave_barrier();   // next row's init vs this row's reads
    }
}

// ----------------------------------------------------------------- cast x ---
__global__ void cast_x(const float* __restrict__ x, u16* __restrict__ xb) {
    size_t i = ((size_t)blockIdx.x * 256 + threadIdx.x) * 4;
    float4 v = *(const float4*)(x + i);
    U16x4 o;
    o.x = f2bf(v.x); o.y = f2bf(v.y); o.z = f2bf(v.z); o.w = f2bf(v.w);
    *(U16x4*)(xb + i) = o;
}

// ------------------------------------------------------------------ GEMM ----
// C[m,n] = sum_k A[m,k] * B[n,k] + bias[n]   (A: M x K, B: N x K, both bf16)
//
// m201-derived 4-phase/K-tile schedule with SHIFTED staging. 256x256 tile,
// 512 thr / 8 waves (2M x 4N, wave tile 128x64), BK=64, 2-slot dbuf where
// each slot splits into two K-HALVES (k0 = cols [0,32), k1 = [32,64)) of
// 256 rows x 32 cols = 16 KB each. Phases consume k-halves in order:
//   P1: ks0 x acc-cols{0,1} (10 ds_read)   P2: ks0 x {2,3} (2)
//   P3: ks1 x {0,1} (10)                   P4: ks1 x {2,3} (2)
// Staging runs ONE PHASE SHIFTED so every half has >=3 phases (~1200+ cyc)
// of lead over its gate (R2/R3's failure was 2-phase lead < HBM latency):
//   P4(u-1): Ak0(u+1); P1(u): Bk0(u+1); P2(u): Ak1(u+1); P3(u): Bk1(u+1).
// Gates (issue-ledger exact, oldest-first retirement):
//   P2(u): in-flight {Ak1(u),Bk1(u),Ak0(u+1),Bk0(u+1),Ak1(u+1)} = 10 loads,
//          vmcnt(6) retires {Ak1,Bk1}(u) -> P3 reads safe.
//   P4(u): in-flight {Ak0,Bk0,Ak1,Bk1}(u+1) + Ak0(u+2) = 10, vmcnt(6)
//          retires {Ak0,Bk0}(u+1) -> next P1 reads safe.
// Tail: P4(NT-2) -> vmcnt(4); P2(NT-1) -> vmcnt(0). Never drains mid-loop.
// WAR safety: each region's last ds_read completes (reader lgkmcnt(0)
// before its MFMA) >=1 barrier before the phase that overwrites it.
// Swizzle: stored chunk sc of row r holds global chunk sc^((r>>1)&3)
// (pre-swizzled source; linear gl_lds dest); read term folds to
// lq^((lrow>>1)&3) -> quarter-wave b128 = 2-way per bank = free.
__global__ __launch_bounds__(512, 2) void gemm_bt(
    const u16* __restrict__ A, const u16* __restrict__ B,
    const float* __restrict__ bias, float* __restrict__ C) {
    constexpr int K = IN_F;
    constexpr int N = OUT_F;
    constexpr int NT = K / 64;                         // 64 K-tiles
    __shared__ __align__(16) u16 As[2][2][256 * 32];   // [slot][khalf] 64 KB
    __shared__ __align__(16) u16 Bs[2][2][256 * 32];   // 64 KB

    const int tid  = threadIdx.x;
    const int wave = tid >> 6, lane = tid & 63;
    const int lrow = lane & 15, lq = lane >> 4;
    const int wm = wave >> 2, wn = wave & 3;           // 2x4 wave grid
    const int swz = (lq ^ ((lrow >> 1) & 3)) << 3;     // folded read swizzle

    // XCD-bijective swizzle (512 wgs % 8 == 0)
    const int wg = (blockIdx.x & 7) * 64 + (blockIdx.x >> 3);
    const int mt = wg & 31, nt = wg >> 5;
    const int m0 = mt * 256, n0 = nt * 256;

    // staging: thread -> row tid>>2 (+128 for round 1), stored chunk tid&3
    // holding global chunk (tid&3)^((tid>>3)&3) of the k-half.
    const int srow = tid >> 2;
    const int gch  = (tid & 3) ^ ((tid >> 3) & 3);
    const u16* pA = A + (size_t)(m0 + srow) * K + gch * 8;
    const u16* pB = B + (size_t)(n0 + srow) * K + gch * 8;

#define STG_A(slot, t, h) do {                                                 \
        gl_lds16(pA + (t) * 64 + (h) * 32, &As[slot][h][wave << 9]);           \
        gl_lds16(pA + (size_t)128 * K + (t) * 64 + (h) * 32,                   \
                 &As[slot][h][4096 + (wave << 9)]);                            \
    } while (0)
#define STG_B(slot, t, h) do {                                                 \
        gl_lds16(pB + (t) * 64 + (h) * 32, &Bs[slot][h][wave << 9]);           \
        gl_lds16(pB + (size_t)128 * K + (t) * 64 + (h) * 32,                   \
                 &Bs[slot][h][4096 + (wave << 9)]);                            \
    } while (0)

#define RD_A(dst, asp) do {                                                    \
        _Pragma("unroll")                                                      \
        for (int mi_ = 0; mi_ < 8; ++mi_) {                                    \
            const int ar_ = (wm << 7) + (mi_ << 4) + lrow;                     \
            dst[mi_] = *(const bf16x8*)&(asp)[ar_ * 32 + swz];                 \
        }                                                                      \
    } while (0)
#define RD_B(bsp, nj) (*(const bf16x8*)&(bsp)[((wn << 6) + ((nj) << 4) + lrow) * 32 + swz])

#define MFQ(av, bx, by, c0, c1) do {                                           \
        __builtin_amdgcn_s_setprio(1);                                         \
        _Pragma("unroll")                                                      \
        for (int mi_ = 0; mi_ < 8; ++mi_) {                                    \
            acc[mi_][c0] = __builtin_amdgcn_mfma_f32_16x16x32_bf16(            \
                av[mi_], bx, acc[mi_][c0], 0, 0, 0);                           \
            acc[mi_][c1] = __builtin_amdgcn_mfma_f32_16x16x32_bf16(            \
                av[mi_], by, acc[mi_][c1], 0, 0, 0);                           \
        }                                                                      \
        __builtin_amdgcn_s_setprio(0);                                         \
    } while (0)

#define BAR1() do { asm volatile("" ::: "memory");                             \
        __builtin_amdgcn_s_barrier();                                          \
        asm volatile("s_waitcnt lgkmcnt(0)" ::: "memory"); } while (0)
#define BAR2() do { asm volatile("" ::: "memory");                             \
        __builtin_amdgcn_s_barrier();                                          \
        asm volatile("" ::: "memory"); } while (0)

    f32x4 acc[8][4];
#pragma unroll
    for (int i = 0; i < 8; ++i)
#pragma unroll
        for (int j = 0; j < 4; ++j) acc[i][j] = (f32x4){0.f, 0.f, 0.f, 0.f};

    // prologue: issue in retirement order Ak0(0),Bk0(0),Ak1(0),Bk1(0),Ak0(1)
    STG_A(0, 0, 0); STG_B(0, 0, 0);
    STG_A(0, 0, 1); STG_B(0, 0, 1);
    STG_A(1, 1, 0);
    asm volatile("s_waitcnt vmcnt(6)" ::: "memory");   // retire Ak0(0),Bk0(0)
    __builtin_amdgcn_s_barrier();
    asm volatile("" ::: "memory");

    for (int u = 0; u < NT; ++u) {
        const u16* as0 = &As[u & 1][0][0];
        const u16* as1 = &As[u & 1][1][0];
        const u16* bs0 = &Bs[u & 1][0][0];
        const u16* bs1 = &Bs[u & 1][1][0];
        const int sn = (u + 1) & 1;
        bf16x8 a0[8], a1[8], b0, b1, b2, b3;

        // ---- P1: ks0 x cols{0,1}; stage Bk0(u+1)
        RD_A(a0, as0);
        b0 = RD_B(bs0, 0); b1 = RD_B(bs0, 1);
        if (u + 1 < NT) STG_B(sn, u + 1, 0);
        BAR1();
        MFQ(a0, b0, b1, 0, 1);
        BAR2();

        // ---- P2: ks0 x cols{2,3}; stage Ak1(u+1); gate {Ak1,Bk1}(u)
        b2 = RD_B(bs0, 2); b3 = RD_B(bs0, 3);
        if (u + 1 < NT) STG_A(sn, u + 1, 1);
        if (u < NT - 1) asm volatile("s_waitcnt vmcnt(6)" ::: "memory");
        else            asm volatile("s_waitcnt vmcnt(0)" ::: "memory");
        BAR1();
        MFQ(a0, b2, b3, 2, 3);
        BAR2();

        // ---- P3: ks1 x cols{0,1}; stage Bk1(u+1)
        RD_A(a1, as1);
        b0 = RD_B(bs1, 0); b1 = RD_B(bs1, 1);
        if (u + 1 < NT) STG_B(sn, u + 1, 1);
        BAR1();
        MFQ(a1, b0, b1, 0, 1);
        BAR2();

        // ---- P4: ks1 x cols{2,3}; stage Ak0(u+2); gate {Ak0,Bk0}(u+1)
        b2 = RD_B(bs1, 2); b3 = RD_B(bs1, 3);
        if (u + 2 < NT) STG_A(u & 1, u + 2, 0);
        if (u < NT - 2)       asm volatile("s_waitcnt vmcnt(6)" ::: "memory");
        else if (u == NT - 2) asm volatile("s_waitcnt vmcnt(4)" ::: "memory");
        BAR1();
        MFQ(a1, b2, b3, 2, 3);
        BAR2();
    }

#undef STG_A
#undef STG_B
#undef RD_A
#undef RD_B
#undef MFQ
#undef BAR1
#undef BAR2

    // epilogue: C/D layout col = lane&15, row = (lane>>4)*4 + reg
#pragma unroll
    for (int mi = 0; mi < 8; ++mi) {
        int rb = m0 + wm * 128 + mi * 16 + lq * 4;
#pragma unroll
        for (int nj = 0; nj < 4; ++nj) {
            int col = n0 + wn * 64 + nj * 16 + lrow;
            float bv = bias[col];
#pragma unroll
            for (int r = 0; r < 4; ++r)
                C[(size_t)(rb + r) * N + col] = acc[mi][nj][r] + bv;
        }
    }
}

// ---------------------------------------------------------------- launch ----
extern "C" void kernel_launch(void* const* d_in, const int* in_sizes, int n_in,
                              void* d_out, int out_size, void* d_ws, size_t ws_size,
                              hipStream_t stream) {
    const float* x    = (const float*)d_in[0];
    const float* w    = (const float*)d_in[1];
    const float* bias = (const float*)d_in[2];
    const float* cs   = (const float*)d_in[3];
    const float* th   = (const float*)d_in[4];
    const float* qs   = (const float*)d_in[5];
    const float* qzp  = (const float*)d_in[6];
    const int*   pr   = (const int*)d_in[7];
    float* out = (float*)d_out;

    char* ws = (char*)d_ws;
    double* ctab = (double*)ws;                                  // 64 KB
    double* stab = (double*)(ws + 65536);                        // 64 KB
    u16*    xb   = (u16*)(ws + 131072);                          // 64 MB
    u16*    wb   = (u16*)(ws + 131072 + (size_t)N_TOK * IN_F * 2);  // 32 MB

    hipLaunchKernelGGL(make_tabs, dim3((NSTAGE * NPAIRS + 255) / 256), dim3(256),
                       0, stream, th, ctab, stab);
    hipLaunchKernelGGL(build_w, dim3(OUT_F / ROWS_PW * 32 / 4), dim3(256),
                       0, stream, w, cs, qs, qzp, pr, ctab, stab, wb);
    hipLaunchKernelGGL(cast_x, dim3(N_TOK * IN_F / 4 / 256), dim3(256), 0, stream,
                       x, xb);
    hipLaunchKernelGGL(gemm_bt, dim3((N_TOK / 256) * (OUT_F / 256)), dim3(512),
                       0, stream, xb, wb, bias, out);
}